// Round 1
// baseline (4872.985 us; speedup 1.0000x reference)
//
#include <hip/hip_runtime.h>
#include <math.h>

#define S_LEN 2048
#define DMODEL 1024
#define NHEAD 16
#define DHEAD 64
#define LN_EPS 1e-5f

// ---------------------------------------------------------------------------
// Kernel 1: QKV projections.  C[4096,1024] = X @ W + b, scattered per-head.
// Q,K -> [bh][s][64]; V -> transposed [bh][64][s] (for conflict-free PV LDS).
// grid (64,16,3), block 256. Tiles: BM=64, BN=64, BK=16, 4x4 per thread.
// ---------------------------------------------------------------------------
__global__ __launch_bounds__(256) void qkv_proj_kernel(
    const float* __restrict__ q, const float* __restrict__ k_in, const float* __restrict__ v,
    const float* __restrict__ Wq, const float* __restrict__ bq,
    const float* __restrict__ Wk, const float* __restrict__ bk,
    const float* __restrict__ Wv, const float* __restrict__ bv,
    float* __restrict__ Qh, float* __restrict__ Kh, float* __restrict__ Vt)
{
    __shared__ __align__(16) float Xs[16][68];   // [k][m], pad for banks/alignment
    __shared__ __align__(16) float Ws[16][68];   // [k][n]
    const int t  = threadIdx.x;
    const int tx = t & 15, ty = t >> 4;
    const int m0 = blockIdx.x * 64, n0 = blockIdx.y * 64;
    const int z  = blockIdx.z;
    const float* X    = (z == 0) ? q  : (z == 1) ? k_in : v;
    const float* W    = (z == 0) ? Wq : (z == 1) ? Wk   : Wv;
    const float* bias = (z == 0) ? bq : (z == 1) ? bk   : bv;

    float c[4][4] = {};
    for (int kt = 0; kt < 64; ++kt) {
        const int k0 = kt * 16;
        __syncthreads();
        #pragma unroll
        for (int i = 0; i < 4; ++i) {
            int e = t + i * 256;                       // 1024 elems: m=e>>4, k=e&15
            Xs[e & 15][e >> 4] = X[(size_t)(m0 + (e >> 4)) * DMODEL + (k0 + (e & 15))];
        }
        #pragma unroll
        for (int i = 0; i < 4; ++i) {
            int e = t + i * 256;                       // 1024 elems: k=e>>6, n=e&63
            Ws[e >> 6][e & 63] = W[(size_t)(k0 + (e >> 6)) * DMODEL + (n0 + (e & 63))];
        }
        __syncthreads();
        #pragma unroll
        for (int p = 0; p < 16; ++p) {
            float4 x4 = *(const float4*)&Xs[p][ty * 4];   // broadcast per ty
            float4 w4 = *(const float4*)&Ws[p][tx * 4];
            float xa[4] = {x4.x, x4.y, x4.z, x4.w};
            float wa[4] = {w4.x, w4.y, w4.z, w4.w};
            #pragma unroll
            for (int i = 0; i < 4; ++i)
                #pragma unroll
                for (int j = 0; j < 4; ++j)
                    c[i][j] += xa[i] * wa[j];
        }
    }
    const int h = n0 >> 6;                             // whole block is one head
    #pragma unroll
    for (int i = 0; i < 4; ++i) {
        int m = m0 + ty * 4 + i;
        int b = m >> 11, s = m & 2047;
        int bh = b * NHEAD + h;
        if (z == 2) {
            #pragma unroll
            for (int j = 0; j < 4; ++j) {
                int d = tx * 4 + j;
                Vt[((size_t)bh * DHEAD + d) * S_LEN + s] = c[i][j] + bias[n0 + d];
            }
        } else {
            int d0 = tx * 4;
            float4 val;
            val.x = c[i][0] + bias[n0 + d0 + 0];
            val.y = c[i][1] + bias[n0 + d0 + 1];
            val.z = c[i][2] + bias[n0 + d0 + 2];
            val.w = c[i][3] + bias[n0 + d0 + 3];
            float* dst = ((z == 0) ? Qh : Kh) + ((size_t)bh * S_LEN + s) * DHEAD + d0;
            *(float4*)dst = val;
        }
    }
}

// ---------------------------------------------------------------------------
// Kernel 2: attention. One block = one (bh, 4 query rows). 256 thr = 4 waves,
// wave w owns query row q0+w (lane-wide shuffles for softmax).
// Phase 1: scores (q in regs, K tiles in LDS pad-65 -> 2-way only, free).
// Phase 2: softmax, write normalized probs to d_out attn (coalesced).
// Phase 3: PV from LDS V tiles (V pre-transposed so lane=d reads are 2-way).
// LDS: 16.64 KB tile + 32 KB scores = 49.4 KB -> 3 blocks/CU.
// ---------------------------------------------------------------------------
__global__ __launch_bounds__(256) void attn_kernel(
    const float* __restrict__ Qh, const float* __restrict__ Kh, const float* __restrict__ Vt,
    const unsigned char* __restrict__ mask,
    float* __restrict__ attn_out,   // [BH][S][S] region of d_out
    float* __restrict__ Oh)         // [B*S][1024] head-concat attention output
{
    __shared__ __align__(16) float KV[64 * 65];   // K tile [64][65] / V tile [64][65]
    __shared__ __align__(16) float Ss[4][S_LEN];  // fp32 scores/probs per row
    const int t    = threadIdx.x;
    const int wv   = t >> 6;          // local row 0..3 (= wave)
    const int lane = t & 63;
    const int q0   = blockIdx.x * 4;
    const int bh   = blockIdx.y;
    const int b    = bh >> 4;
    const int row  = q0 + wv;

    // q row into registers (broadcast loads, L1/L2-served)
    float4 qreg[16];
    const float4* qrow = (const float4*)(Qh + ((size_t)bh * S_LEN + row) * DHEAD);
    #pragma unroll
    for (int i = 0; i < 16; ++i) qreg[i] = qrow[i];

    const unsigned char* mrow = mask + ((size_t)b * S_LEN + row) * S_LEN;

    // ---- Phase 1: scores ----
    for (int jt = 0; jt < 32; ++jt) {
        const int jb = jt * 64;
        __syncthreads();
        #pragma unroll
        for (int i = 0; i < 4; ++i) {                 // 64x64 floats = 1024 f4
            int e  = t + i * 256;
            int j  = e >> 4, d4 = e & 15;
            float4 kv4 = *(const float4*)(Kh + ((size_t)bh * S_LEN + jb + j) * DHEAD + d4 * 4);
            float* dst = &KV[j * 65 + d4 * 4];
            dst[0] = kv4.x; dst[1] = kv4.y; dst[2] = kv4.z; dst[3] = kv4.w;
        }
        __syncthreads();
        const float* Kr = &KV[lane * 65];             // banks (lane+d)%32: 2-way, free
        float s = 0.f;
        #pragma unroll
        for (int d4 = 0; d4 < 16; ++d4) {
            float4 qv = qreg[d4];
            s += qv.x * Kr[d4*4+0] + qv.y * Kr[d4*4+1] + qv.z * Kr[d4*4+2] + qv.w * Kr[d4*4+3];
        }
        int j = jb + lane;
        Ss[wv][j] = mrow[j] ? -INFINITY : s * 0.125f; // scale = 1/sqrt(64)
    }

    // ---- Phase 2: softmax (row-private; wave-wide reductions) ----
    float mx = -INFINITY;
    for (int j = lane; j < S_LEN; j += 64) mx = fmaxf(mx, Ss[wv][j]);
    #pragma unroll
    for (int off = 32; off > 0; off >>= 1) mx = fmaxf(mx, __shfl_xor(mx, off));
    float sum = 0.f;
    for (int j = lane; j < S_LEN; j += 64) {
        float e = __expf(Ss[wv][j] - mx);
        Ss[wv][j] = e;
        sum += e;
    }
    #pragma unroll
    for (int off = 32; off > 0; off >>= 1) sum += __shfl_xor(sum, off);
    const float inv = 1.0f / sum;
    float* arow = attn_out + ((size_t)bh * S_LEN + row) * S_LEN;
    for (int j = lane; j < S_LEN; j += 64) {
        float p = Ss[wv][j] * inv;
        Ss[wv][j] = p;
        arow[j] = p;                                   // coalesced 256B stores
    }

    // ---- Phase 3: PV (lane = output d) ----
    float acc = 0.f;
    for (int jt = 0; jt < 32; ++jt) {
        const int jb = jt * 64;
        __syncthreads();                               // all waves done with prev tile
        #pragma unroll
        for (int i = 0; i < 4; ++i) {                  // V tile 64d x 64j
            int e  = t + i * 256;
            int d  = e >> 4, j4 = e & 15;
            float4 vv = *(const float4*)(Vt + ((size_t)bh * DHEAD + d) * S_LEN + jb + j4 * 4);
            float* dst = &KV[d * 65 + j4 * 4];
            dst[0] = vv.x; dst[1] = vv.y; dst[2] = vv.z; dst[3] = vv.w;
        }
        __syncthreads();
        const float* Vr = &KV[lane * 65];              // lane = d, 2-way only
        const float* Pr = &Ss[wv][jb];
        #pragma unroll
        for (int j4 = 0; j4 < 16; ++j4) {
            float4 p4 = *(const float4*)(Pr + j4 * 4); // broadcast per wave
            acc += p4.x * Vr[j4*4+0] + p4.y * Vr[j4*4+1] + p4.z * Vr[j4*4+2] + p4.w * Vr[j4*4+3];
        }
    }
    const int h = bh & 15;
    Oh[((size_t)(b * S_LEN + row)) * DMODEL + h * DHEAD + lane] = acc;
}

// ---------------------------------------------------------------------------
// Kernel 3: output projection + bias + residual.  Y = Oh @ Wo + bo + q
// grid (64,16), block 256. Same tiling as kernel 1.
// ---------------------------------------------------------------------------
__global__ __launch_bounds__(256) void out_proj_kernel(
    const float* __restrict__ Xin, const float* __restrict__ Wo, const float* __restrict__ bo,
    const float* __restrict__ resid, float* __restrict__ Y)
{
    __shared__ __align__(16) float Xs[16][68];
    __shared__ __align__(16) float Ws[16][68];
    const int t  = threadIdx.x;
    const int tx = t & 15, ty = t >> 4;
    const int m0 = blockIdx.x * 64, n0 = blockIdx.y * 64;

    float c[4][4] = {};
    for (int kt = 0; kt < 64; ++kt) {
        const int k0 = kt * 16;
        __syncthreads();
        #pragma unroll
        for (int i = 0; i < 4; ++i) {
            int e = t + i * 256;
            Xs[e & 15][e >> 4] = Xin[(size_t)(m0 + (e >> 4)) * DMODEL + (k0 + (e & 15))];
        }
        #pragma unroll
        for (int i = 0; i < 4; ++i) {
            int e = t + i * 256;
            Ws[e >> 6][e & 63] = Wo[(size_t)(k0 + (e >> 6)) * DMODEL + (n0 + (e & 63))];
        }
        __syncthreads();
        #pragma unroll
        for (int p = 0; p < 16; ++p) {
            float4 x4 = *(const float4*)&Xs[p][ty * 4];
            float4 w4 = *(const float4*)&Ws[p][tx * 4];
            float xa[4] = {x4.x, x4.y, x4.z, x4.w};
            float wa[4] = {w4.x, w4.y, w4.z, w4.w};
            #pragma unroll
            for (int i = 0; i < 4; ++i)
                #pragma unroll
                for (int j = 0; j < 4; ++j)
                    c[i][j] += xa[i] * wa[j];
        }
    }
    #pragma unroll
    for (int i = 0; i < 4; ++i) {
        int m = m0 + ty * 4 + i;
        size_t base = (size_t)m * DMODEL + n0 + tx * 4;
        float4 r4 = *(const float4*)(resid + base);
        float4 val;
        val.x = c[i][0] + bo[n0 + tx*4 + 0] + r4.x;
        val.y = c[i][1] + bo[n0 + tx*4 + 1] + r4.y;
        val.z = c[i][2] + bo[n0 + tx*4 + 2] + r4.z;
        val.w = c[i][3] + bo[n0 + tx*4 + 3] + r4.w;
        *(float4*)(Y + base) = val;
    }
}

// ---------------------------------------------------------------------------
// Kernel 4: LayerNorm per row (biased variance, eps inside rsqrt).
// grid 4096, block 256; each thread owns one float4 of the row.
// ---------------------------------------------------------------------------
__global__ __launch_bounds__(256) void ln_kernel(
    const float* __restrict__ Y, const float* __restrict__ gamma,
    const float* __restrict__ beta, float* __restrict__ out)
{
    const int row  = blockIdx.x;
    const int t    = threadIdx.x;
    const int lane = t & 63, wv = t >> 6;
    float4 x = ((const float4*)(Y + (size_t)row * DMODEL))[t];
    float s  = x.x + x.y + x.z + x.w;
    float sq = x.x*x.x + x.y*x.y + x.z*x.z + x.w*x.w;
    #pragma unroll
    for (int off = 32; off > 0; off >>= 1) {
        s  += __shfl_xor(s, off);
        sq += __shfl_xor(sq, off);
    }
    __shared__ float rs[4], rq[4];
    if (lane == 0) { rs[wv] = s; rq[wv] = sq; }
    __syncthreads();
    float S = rs[0] + rs[1] + rs[2] + rs[3];
    float Q = rq[0] + rq[1] + rq[2] + rq[3];
    float mu   = S * (1.0f / DMODEL);
    float var  = Q * (1.0f / DMODEL) - mu * mu;
    float rstd = rsqrtf(var + LN_EPS);
    float4 g  = ((const float4*)gamma)[t];
    float4 be = ((const float4*)beta)[t];
    float4 o;
    o.x = (x.x - mu) * rstd * g.x + be.x;
    o.y = (x.y - mu) * rstd * g.y + be.y;
    o.z = (x.z - mu) * rstd * g.z + be.z;
    o.w = (x.w - mu) * rstd * g.w + be.w;
    ((float4*)(out + (size_t)row * DMODEL))[t] = o;
}

// ---------------------------------------------------------------------------
extern "C" void kernel_launch(void* const* d_in, const int* in_sizes, int n_in,
                              void* d_out, int out_size, void* d_ws, size_t ws_size,
                              hipStream_t stream)
{
    const float* q    = (const float*)d_in[0];
    const float* k    = (const float*)d_in[1];
    const float* v    = (const float*)d_in[2];
    const unsigned char* mask = (const unsigned char*)d_in[3];
    const float* Wq   = (const float*)d_in[4];
    const float* bq   = (const float*)d_in[5];
    const float* Wk   = (const float*)d_in[6];
    const float* bk   = (const float*)d_in[7];
    const float* Wv   = (const float*)d_in[8];
    const float* bv   = (const float*)d_in[9];
    const float* Wo   = (const float*)d_in[10];
    const float* bo   = (const float*)d_in[11];
    const float* lng  = (const float*)d_in[12];
    const float* lnb  = (const float*)d_in[13];

    const size_t NTOK = (size_t)2 * S_LEN;           // 4096 rows
    const size_t HSZ  = NTOK * DMODEL;               // 4,194,304 floats per buffer
    float* ws   = (float*)d_ws;
    float* Qh   = ws;                                // [bh][s][64]
    float* Kh   = ws + HSZ;                          // [bh][s][64]
    float* Vt   = ws + 2 * HSZ;                      // [bh][64][s]
    float* Oh   = ws + 3 * HSZ;                      // [b*s][1024]
    float* Ytmp = ws;                                // reuse Qh region after attn

    float* out0 = (float*)d_out;                     // [B,S,1024]
    float* attn = out0 + HSZ;                        // [B,H,S,S]

    qkv_proj_kernel<<<dim3(64, 16, 3), 256, 0, stream>>>(q, k, v, Wq, bq, Wk, bk, Wv, bv,
                                                         Qh, Kh, Vt);
    attn_kernel<<<dim3(S_LEN / 4, 32), 256, 0, stream>>>(Qh, Kh, Vt, mask, attn, Oh);
    out_proj_kernel<<<dim3(64, 16), 256, 0, stream>>>(Oh, Wo, bo, q, Ytmp);
    ln_kernel<<<dim3(4096), 256, 0, stream>>>(Ytmp, lng, lnb, out0);
}